// Round 1
// baseline (916.562 us; speedup 1.0000x reference)
//
#include <hip/hip_runtime.h>
#include <math.h>

#define NN 50000
#define EE 500000
#define ETOT (EE + NN)
#define NG 64

// ---------------- histogram of dst + per-graph node counts ----------------
__global__ void k_hist(const int* __restrict__ ei, const int* __restrict__ batch,
                       int* __restrict__ counts, int* __restrict__ gcount) {
    int t = blockIdx.x * 256 + threadIdx.x;
    if (t < ETOT) {
        int dst = (t < EE) ? ei[EE + t] : (t - EE);
        atomicAdd(counts + dst, 1);
    }
    if (t < NN) atomicAdd(gcount + batch[t], 1);
}

// ---------------- exclusive scan over counts -> indptr (single block) -----
__global__ void k_scan(const int* __restrict__ counts, int* __restrict__ indptr) {
    __shared__ int sdata[1024];
    __shared__ int carry_s;
    int tid = threadIdx.x;
    if (tid == 0) carry_s = 0;
    __syncthreads();
    for (int base = 0; base < NN; base += 1024) {
        int i = base + tid;
        int v = (i < NN) ? counts[i] : 0;
        sdata[tid] = v;
        __syncthreads();
        for (int off = 1; off < 1024; off <<= 1) {
            int t = (tid >= off) ? sdata[tid - off] : 0;
            __syncthreads();
            sdata[tid] += t;
            __syncthreads();
        }
        int incl = sdata[tid];
        int carry = carry_s;
        if (i < NN) indptr[i] = carry + incl - v;
        int total = sdata[1023];
        __syncthreads();
        if (tid == 0) carry_s = carry + total;
        __syncthreads();
    }
    if (tid == 0) indptr[NN] = carry_s;
}

// ---------------- GEMM1: h1lin[N,256] = x[N,128] @ W1[256,128]^T ----------
// block = 256 threads, 32 rows/block. xs tile in LDS. 4 rows x 8 cols / thread.
__global__ __launch_bounds__(256) void k_gemm1(const float* __restrict__ x,
                                               const float* __restrict__ W1,
                                               float* __restrict__ h1lin) {
    __shared__ float xs[32 * 128];
    int n0 = blockIdx.x * 32;
    int tid = threadIdx.x;
#pragma unroll
    for (int i = 0; i < 4; ++i) {
        int lin = (i * 256 + tid) * 4;
        int r = lin >> 7, k = lin & 127;
        float4 v = make_float4(0.f, 0.f, 0.f, 0.f);
        if (n0 + r < NN) v = *(const float4*)&x[(size_t)(n0 + r) * 128 + k];
        *(float4*)&xs[lin] = v;
    }
    __syncthreads();
    int c0 = (tid & 31) * 8;
    int r0 = (tid >> 5) * 4;
    float acc[4][8] = {};
    for (int k = 0; k < 128; k += 4) {
        float4 xa[4];
#pragma unroll
        for (int rr = 0; rr < 4; ++rr) xa[rr] = *(const float4*)&xs[(r0 + rr) * 128 + k];
#pragma unroll
        for (int cc = 0; cc < 8; ++cc) {
            float4 w = *(const float4*)&W1[(size_t)(c0 + cc) * 128 + k];
#pragma unroll
            for (int rr = 0; rr < 4; ++rr)
                acc[rr][cc] += xa[rr].x * w.x + xa[rr].y * w.y + xa[rr].z * w.z + xa[rr].w * w.w;
        }
    }
#pragma unroll
    for (int rr = 0; rr < 4; ++rr) {
        int nr = n0 + r0 + rr;
        if (nr < NN) {
            float4 o1 = make_float4(acc[rr][0], acc[rr][1], acc[rr][2], acc[rr][3]);
            float4 o2 = make_float4(acc[rr][4], acc[rr][5], acc[rr][6], acc[rr][7]);
            *(float4*)&h1lin[(size_t)nr * 256 + c0] = o1;
            *(float4*)&h1lin[(size_t)nr * 256 + c0 + 4] = o2;
        }
    }
}

// ---------------- per-node attention logits layer 1 -----------------------
__global__ void k_alpha1(const float* __restrict__ h1lin, const float* __restrict__ att_s,
                         const float* __restrict__ att_d, float* __restrict__ alpha_s,
                         float* __restrict__ alpha_d) {
    int wid = (blockIdx.x * 256 + threadIdx.x) >> 6;
    int l = threadIdx.x & 63;
    if (wid >= NN) return;
    float s[4], d[4];
#pragma unroll
    for (int j = 0; j < 4; ++j) {
        float h = h1lin[(size_t)wid * 256 + j * 64 + l];
        s[j] = h * att_s[j * 64 + l];
        d[j] = h * att_d[j * 64 + l];
    }
#pragma unroll
    for (int m = 32; m > 0; m >>= 1) {
#pragma unroll
        for (int j = 0; j < 4; ++j) {
            s[j] += __shfl_xor(s[j], m);
            d[j] += __shfl_xor(d[j], m);
        }
    }
    if (l == 0) {
#pragma unroll
        for (int j = 0; j < 4; ++j) {
            alpha_s[wid * 4 + j] = s[j];
            alpha_d[wid * 4 + j] = d[j];
        }
    }
}

// ---------------- bucket fill + edge exp + denominators (layer 1) ---------
__global__ void k_fill(const int* __restrict__ ei, const int* __restrict__ indptr,
                       int* __restrict__ cursor, const float* __restrict__ alpha_s,
                       const float* __restrict__ alpha_d, int* __restrict__ src_sorted,
                       int* __restrict__ dst_sorted, float* __restrict__ ee1,
                       float* __restrict__ denom1) {
    int t = blockIdx.x * 256 + threadIdx.x;
    if (t >= ETOT) return;
    int src = (t < EE) ? ei[t] : (t - EE);
    int dst = (t < EE) ? ei[EE + t] : (t - EE);
    int p = indptr[dst] + atomicAdd(cursor + dst, 1);
    src_sorted[p] = src;
    dst_sorted[p] = dst;
#pragma unroll
    for (int j = 0; j < 4; ++j) {
        float v = alpha_s[src * 4 + j] + alpha_d[dst * 4 + j];
        v = v > 0.f ? v : 0.2f * v;
        float e = expf(v);
        ee1[p * 4 + j] = e;
        atomicAdd(denom1 + dst * 4 + j, e);
    }
}

// ---------------- gather-aggregate layer 1 + bias + ELU -------------------
// one wave per dst node; lane l owns channel l of each of the 4 heads.
__global__ void k_gather1(const int* __restrict__ indptr, const int* __restrict__ src_sorted,
                          const float* __restrict__ ee1, const float* __restrict__ denom1,
                          const float* __restrict__ h1lin, const float* __restrict__ b1,
                          float* __restrict__ h1) {
    int wid = (blockIdx.x * 256 + threadIdx.x) >> 6;
    int l = threadIdx.x & 63;
    if (wid >= NN) return;
    int p0 = indptr[wid], p1 = indptr[wid + 1];
    float inv[4];
#pragma unroll
    for (int j = 0; j < 4; ++j) inv[j] = 1.0f / (denom1[wid * 4 + j] + 1e-16f);
    float acc[4] = {0.f, 0.f, 0.f, 0.f};
    for (int p = p0; p < p1; ++p) {
        int s = src_sorted[p];
        const float* hs = &h1lin[(size_t)s * 256 + l];
#pragma unroll
        for (int j = 0; j < 4; ++j) {
            float w = ee1[p * 4 + j] * inv[j];
            acc[j] += w * hs[j * 64];
        }
    }
#pragma unroll
    for (int j = 0; j < 4; ++j) {
        float v = acc[j] + b1[j * 64 + l];
        v = v > 0.f ? v : expm1f(v);
        h1[(size_t)wid * 256 + j * 64 + l] = v;
    }
}

// ---------------- GEMM2 (wave/node) + attention logits layer 2 ------------
__global__ void k_gemm2a(const float* __restrict__ h1, const float* __restrict__ W2,
                         const float* __restrict__ as2v, const float* __restrict__ ad2v,
                         float* __restrict__ h2lin, float* __restrict__ alpha_s2,
                         float* __restrict__ alpha_d2) {
    int wid = (blockIdx.x * 256 + threadIdx.x) >> 6;
    int l = threadIdx.x & 63;
    if (wid >= NN) return;
    float hv[4];
#pragma unroll
    for (int j = 0; j < 4; ++j) hv[j] = h1[(size_t)wid * 256 + j * 64 + l];
    float t[10];
#pragma unroll
    for (int o = 0; o < 10; ++o) {
        float a = 0.f;
#pragma unroll
        for (int j = 0; j < 4; ++j) a += hv[j] * W2[o * 256 + j * 64 + l];
        t[o] = a;
    }
#pragma unroll
    for (int m = 32; m > 0; m >>= 1) {
#pragma unroll
        for (int o = 0; o < 10; ++o) t[o] += __shfl_xor(t[o], m);
    }
    if (l == 0) {
        float as = 0.f, ad = 0.f;
#pragma unroll
        for (int o = 0; o < 10; ++o) {
            h2lin[(size_t)wid * 10 + o] = t[o];
            as += t[o] * as2v[o];
            ad += t[o] * ad2v[o];
        }
        alpha_s2[wid] = as;
        alpha_d2[wid] = ad;
    }
}

// ---------------- edge exp + denominators (layer 2), over sorted edges ----
__global__ void k_ee2(const int* __restrict__ src_sorted, const int* __restrict__ dst_sorted,
                      const float* __restrict__ as2, const float* __restrict__ ad2,
                      float* __restrict__ ee2, float* __restrict__ denom2) {
    int p = blockIdx.x * 256 + threadIdx.x;
    if (p >= ETOT) return;
    int s = src_sorted[p], d = dst_sorted[p];
    float v = as2[s] + ad2[d];
    v = v > 0.f ? v : 0.2f * v;
    float e = expf(v);
    ee2[p] = e;
    atomicAdd(denom2 + d, e);
}

// ---------------- gather layer 2 + bias + fused mean-pool -----------------
__global__ void k_g2pool(const int* __restrict__ indptr, const int* __restrict__ src_sorted,
                         const float* __restrict__ ee2, const float* __restrict__ denom2,
                         const float* __restrict__ h2lin, const float* __restrict__ b2,
                         const int* __restrict__ batch, float* __restrict__ pooled) {
    int t = blockIdx.x * 256 + threadIdx.x;
    bool valid = t < NN;
    float acc[10] = {};
    int g = -1;
    if (valid) {
        int p0 = indptr[t], p1 = indptr[t + 1];
        float inv = 1.0f / (denom2[t] + 1e-16f);
        for (int p = p0; p < p1; ++p) {
            int s = src_sorted[p];
            float w = ee2[p] * inv;
#pragma unroll
            for (int c = 0; c < 10; ++c) acc[c] += w * h2lin[(size_t)s * 10 + c];
        }
#pragma unroll
        for (int c = 0; c < 10; ++c) acc[c] += b2[c];
        g = batch[t];
    }
    int g0 = __shfl(g, 0);
    bool uni = __all((!valid) || (g == g0));
    if (uni) {
        if (g0 >= 0) {
#pragma unroll
            for (int m = 32; m > 0; m >>= 1) {
#pragma unroll
                for (int c = 0; c < 10; ++c) acc[c] += __shfl_xor(acc[c], m);
            }
            if ((threadIdx.x & 63) == 0) {
#pragma unroll
                for (int c = 0; c < 10; ++c) atomicAdd(pooled + g0 * 10 + c, acc[c]);
            }
        }
    } else if (valid) {
#pragma unroll
        for (int c = 0; c < 10; ++c) atomicAdd(pooled + g * 10 + c, acc[c]);
    }
}

// ---------------- mean + log_softmax --------------------------------------
__global__ void k_final(const float* __restrict__ pooled, const int* __restrict__ gcount,
                        float* __restrict__ out) {
    int g = threadIdx.x;
    if (g >= NG) return;
    float c = fmaxf((float)gcount[g], 1.0f);
    float m[10];
    float mx = -1e30f;
#pragma unroll
    for (int i = 0; i < 10; ++i) {
        m[i] = pooled[g * 10 + i] / c;
        mx = fmaxf(mx, m[i]);
    }
    float s = 0.f;
#pragma unroll
    for (int i = 0; i < 10; ++i) s += expf(m[i] - mx);
    float lse = mx + logf(s);
#pragma unroll
    for (int i = 0; i < 10; ++i) out[g * 10 + i] = m[i] - lse;
}

extern "C" void kernel_launch(void* const* d_in, const int* in_sizes, int n_in,
                              void* d_out, int out_size, void* d_ws, size_t ws_size,
                              hipStream_t stream) {
    const float* x   = (const float*)d_in[0];
    const int*   ei  = (const int*)d_in[1];
    const int*   bat = (const int*)d_in[3];
    const float* W1  = (const float*)d_in[4];
    const float* as1 = (const float*)d_in[5];
    const float* ad1 = (const float*)d_in[6];
    const float* b1  = (const float*)d_in[7];
    const float* W2  = (const float*)d_in[8];
    const float* as2 = (const float*)d_in[9];
    const float* ad2 = (const float*)d_in[10];
    const float* b2  = (const float*)d_in[11];
    float* out = (float*)d_out;

    char* ws = (char*)d_ws;
    size_t off = 0;
    auto alloc = [&](size_t bytes) -> size_t {
        size_t o = off;
        off = (off + bytes + 255) & ~(size_t)255;
        return o;
    };
    // zero-initialized region (contiguous, one memset)
    size_t o_counts = alloc((size_t)NN * 4);
    size_t o_cursor = alloc((size_t)NN * 4);
    size_t o_denom1 = alloc((size_t)NN * 4 * 4);
    size_t o_denom2 = alloc((size_t)NN * 4);
    size_t o_pooled = alloc((size_t)NG * 10 * 4);
    size_t o_gcount = alloc((size_t)NG * 4);
    size_t zero_bytes = off;
    // rest
    size_t o_indptr = alloc((size_t)(NN + 1) * 4);
    size_t o_srcs   = alloc((size_t)ETOT * 4);
    size_t o_dsts   = alloc((size_t)ETOT * 4);
    size_t o_ee1    = alloc((size_t)ETOT * 4 * 4);
    size_t o_ee2    = alloc((size_t)ETOT * 4);
    size_t o_h1lin  = alloc((size_t)NN * 256 * 4);
    size_t o_h1     = alloc((size_t)NN * 256 * 4);
    size_t o_als1   = alloc((size_t)NN * 4 * 4);
    size_t o_ald1   = alloc((size_t)NN * 4 * 4);
    size_t o_h2lin  = alloc((size_t)NN * 10 * 4);
    size_t o_als2   = alloc((size_t)NN * 4);
    size_t o_ald2   = alloc((size_t)NN * 4);
    (void)ws_size;

    int*   counts = (int*)(ws + o_counts);
    int*   cursor = (int*)(ws + o_cursor);
    float* denom1 = (float*)(ws + o_denom1);
    float* denom2 = (float*)(ws + o_denom2);
    float* pooled = (float*)(ws + o_pooled);
    int*   gcount = (int*)(ws + o_gcount);
    int*   indptr = (int*)(ws + o_indptr);
    int*   srcs   = (int*)(ws + o_srcs);
    int*   dsts   = (int*)(ws + o_dsts);
    float* ee1    = (float*)(ws + o_ee1);
    float* ee2    = (float*)(ws + o_ee2);
    float* h1lin  = (float*)(ws + o_h1lin);
    float* h1     = (float*)(ws + o_h1);
    float* als1   = (float*)(ws + o_als1);
    float* ald1   = (float*)(ws + o_ald1);
    float* h2lin  = (float*)(ws + o_h2lin);
    float* als2   = (float*)(ws + o_als2);
    float* ald2   = (float*)(ws + o_ald2);

    hipMemsetAsync(ws, 0, zero_bytes, stream);

    int gE = (ETOT + 255) / 256;        // edge-parallel grids
    int gW = (NN + 3) / 4;              // wave-per-node grids (4 waves/block)
    int gN = (NN + 255) / 256;          // thread-per-node grids

    k_hist<<<gE, 256, 0, stream>>>(ei, bat, counts, gcount);
    k_scan<<<1, 1024, 0, stream>>>(counts, indptr);
    k_gemm1<<<(NN + 31) / 32, 256, 0, stream>>>(x, W1, h1lin);
    k_alpha1<<<gW, 256, 0, stream>>>(h1lin, as1, ad1, als1, ald1);
    k_fill<<<gE, 256, 0, stream>>>(ei, indptr, cursor, als1, ald1, srcs, dsts, ee1, denom1);
    k_gather1<<<gW, 256, 0, stream>>>(indptr, srcs, ee1, denom1, h1lin, b1, h1);
    k_gemm2a<<<gW, 256, 0, stream>>>(h1, W2, as2, ad2, h2lin, als2, ald2);
    k_ee2<<<gE, 256, 0, stream>>>(srcs, dsts, als2, ald2, ee2, denom2);
    k_g2pool<<<gN, 256, 0, stream>>>(indptr, srcs, ee2, denom2, h2lin, b2, bat, pooled);
    k_final<<<1, 64, 0, stream>>>(pooled, gcount, out);
    (void)n_in; (void)in_sizes; (void)out_size;
}

// Round 2
// 525.334 us; speedup vs baseline: 1.7447x; 1.7447x over previous
//
#include <hip/hip_runtime.h>
#include <math.h>

#define NN 50000
#define EE 500000
#define ETOT (EE + NN)
#define NG 64

// ---------------- histogram of dst + per-graph node counts ----------------
__global__ void k_hist(const int* __restrict__ ei, const int* __restrict__ batch,
                       int* __restrict__ counts, int* __restrict__ gcount) {
    int t = blockIdx.x * 256 + threadIdx.x;
    if (t < ETOT) {
        int dst = (t < EE) ? ei[EE + t] : (t - EE);
        atomicAdd(counts + dst, 1);
    }
    if (t < NN) {
        int g = batch[t];
        // batch is sorted -> waves are (nearly) uniform. Aggregate per wave.
        int g0 = __shfl(g, 0);
        bool same = (g == g0);
        unsigned long long m = __ballot(same);
        if (same) {
            if ((threadIdx.x & 63) == (__ffsll((long long)m) - 1))
                atomicAdd(gcount + g0, (int)__popcll(m));
        } else {
            atomicAdd(gcount + g, 1);
        }
    }
}

// ---------------- exclusive scan counts -> indptr (+ seed cursor) ---------
__global__ void k_scan(const int* __restrict__ counts, int* __restrict__ indptr,
                       int* __restrict__ cursor) {
    __shared__ int wsum[16];
    __shared__ int carry_s;
    int tid = threadIdx.x;
    int lane = tid & 63;
    int w = tid >> 6;
    if (tid == 0) carry_s = 0;
    __syncthreads();
    for (int base = 0; base < NN; base += 1024) {
        int i = base + tid;
        int v = (i < NN) ? counts[i] : 0;
        // inclusive wave scan
        int s = v;
#pragma unroll
        for (int off = 1; off < 64; off <<= 1) {
            int u = __shfl_up(s, off);
            if (lane >= off) s += u;
        }
        if (lane == 63) wsum[w] = s;
        __syncthreads();
        if (w == 0) {
            int t2 = (lane < 16) ? wsum[lane] : 0;
#pragma unroll
            for (int off = 1; off < 16; off <<= 1) {
                int u = __shfl_up(t2, off);
                if (lane >= off) t2 += u;
            }
            if (lane < 16) wsum[lane] = t2;
        }
        __syncthreads();
        int wpre = (w == 0) ? 0 : wsum[w - 1];
        int incl = s + wpre;
        int carry = carry_s;
        if (i < NN) {
            int excl = carry + incl - v;
            indptr[i] = excl;
            cursor[i] = excl;
        }
        __syncthreads();
        if (tid == 1023) carry_s = carry + incl;
        __syncthreads();
    }
    if (tid == 0) indptr[NN] = carry_s;
}

// ---------------- GEMM1: h1lin[N,256] = x[N,128] @ W1[256,128]^T ----------
__global__ __launch_bounds__(256) void k_gemm1(const float* __restrict__ x,
                                               const float* __restrict__ W1,
                                               float* __restrict__ h1lin) {
    __shared__ float xs[32 * 128];
    int n0 = blockIdx.x * 32;
    int tid = threadIdx.x;
#pragma unroll
    for (int i = 0; i < 4; ++i) {
        int lin = (i * 256 + tid) * 4;
        int r = lin >> 7, k = lin & 127;
        float4 v = make_float4(0.f, 0.f, 0.f, 0.f);
        if (n0 + r < NN) v = *(const float4*)&x[(size_t)(n0 + r) * 128 + k];
        *(float4*)&xs[lin] = v;
    }
    __syncthreads();
    int c0 = (tid & 31) * 8;
    int r0 = (tid >> 5) * 4;
    float acc[4][8] = {};
    for (int k = 0; k < 128; k += 4) {
        float4 xa[4];
#pragma unroll
        for (int rr = 0; rr < 4; ++rr) xa[rr] = *(const float4*)&xs[(r0 + rr) * 128 + k];
#pragma unroll
        for (int cc = 0; cc < 8; ++cc) {
            float4 wv = *(const float4*)&W1[(size_t)(c0 + cc) * 128 + k];
#pragma unroll
            for (int rr = 0; rr < 4; ++rr)
                acc[rr][cc] += xa[rr].x * wv.x + xa[rr].y * wv.y + xa[rr].z * wv.z + xa[rr].w * wv.w;
        }
    }
#pragma unroll
    for (int rr = 0; rr < 4; ++rr) {
        int nr = n0 + r0 + rr;
        if (nr < NN) {
            float4 o1 = make_float4(acc[rr][0], acc[rr][1], acc[rr][2], acc[rr][3]);
            float4 o2 = make_float4(acc[rr][4], acc[rr][5], acc[rr][6], acc[rr][7]);
            *(float4*)&h1lin[(size_t)nr * 256 + c0] = o1;
            *(float4*)&h1lin[(size_t)nr * 256 + c0 + 4] = o2;
        }
    }
}

// ---------------- per-node attention logits layer 1 -----------------------
__global__ void k_alpha1(const float* __restrict__ h1lin, const float* __restrict__ att_s,
                         const float* __restrict__ att_d, float* __restrict__ alpha_s,
                         float* __restrict__ alpha_d) {
    int wid = (blockIdx.x * 256 + threadIdx.x) >> 6;
    int l = threadIdx.x & 63;
    if (wid >= NN) return;
    float s[4], d[4];
#pragma unroll
    for (int j = 0; j < 4; ++j) {
        float h = h1lin[(size_t)wid * 256 + j * 64 + l];
        s[j] = h * att_s[j * 64 + l];
        d[j] = h * att_d[j * 64 + l];
    }
#pragma unroll
    for (int m = 32; m > 0; m >>= 1) {
#pragma unroll
        for (int j = 0; j < 4; ++j) {
            s[j] += __shfl_xor(s[j], m);
            d[j] += __shfl_xor(d[j], m);
        }
    }
    if (l == 0) {
#pragma unroll
        for (int j = 0; j < 4; ++j) {
            alpha_s[wid * 4 + j] = s[j];
            alpha_d[wid * 4 + j] = d[j];
        }
    }
}

// ---------------- bucket fill (CSR column indices) ------------------------
__global__ void k_fill(const int* __restrict__ ei, int* __restrict__ cursor,
                       int* __restrict__ srcs) {
    int t = blockIdx.x * 256 + threadIdx.x;
    if (t >= ETOT) return;
    int src = (t < EE) ? ei[t] : (t - EE);
    int dst = (t < EE) ? ei[EE + t] : (t - EE);
    int p = atomicAdd(cursor + dst, 1);
    srcs[p] = src;
}

// ---------------- gather-aggregate layer 1 + softmax + bias + ELU ---------
// one wave per dst node; lane l owns channel l of each of the 4 heads.
__global__ void k_gather1(const int* __restrict__ indptr, const int* __restrict__ srcs,
                          const float* __restrict__ alpha_s, const float* __restrict__ alpha_d,
                          const float* __restrict__ h1lin, const float* __restrict__ b1,
                          float* __restrict__ h1) {
    int wid = (blockIdx.x * 256 + threadIdx.x) >> 6;
    int l = threadIdx.x & 63;
    if (wid >= NN) return;
    int p0 = indptr[wid], p1 = indptr[wid + 1];
    float4 ad = *(const float4*)&alpha_d[wid * 4];
    float acc[4] = {0.f, 0.f, 0.f, 0.f};
    float dsum[4] = {0.f, 0.f, 0.f, 0.f};
    for (int p = p0; p < p1; ++p) {
        int s = srcs[p];
        float4 as = *(const float4*)&alpha_s[s * 4];
        float e[4];
        e[0] = as.x + ad.x; e[1] = as.y + ad.y; e[2] = as.z + ad.z; e[3] = as.w + ad.w;
        const float* hs = &h1lin[(size_t)s * 256 + l];
#pragma unroll
        for (int j = 0; j < 4; ++j) {
            float v = e[j] > 0.f ? e[j] : 0.2f * e[j];
            float w = __expf(v);
            dsum[j] += w;
            acc[j] += w * hs[j * 64];
        }
    }
#pragma unroll
    for (int j = 0; j < 4; ++j) {
        float v = acc[j] / dsum[j] + b1[j * 64 + l];
        v = v > 0.f ? v : expm1f(v);
        h1[(size_t)wid * 256 + j * 64 + l] = v;
    }
}

// ---------------- GEMM2 (wave/node) + attention logits layer 2 ------------
__global__ void k_gemm2a(const float* __restrict__ h1, const float* __restrict__ W2,
                         const float* __restrict__ as2v, const float* __restrict__ ad2v,
                         float* __restrict__ h2lin, float* __restrict__ alpha_s2,
                         float* __restrict__ alpha_d2) {
    int wid = (blockIdx.x * 256 + threadIdx.x) >> 6;
    int l = threadIdx.x & 63;
    if (wid >= NN) return;
    float hv[4];
#pragma unroll
    for (int j = 0; j < 4; ++j) hv[j] = h1[(size_t)wid * 256 + j * 64 + l];
    float t[10];
#pragma unroll
    for (int o = 0; o < 10; ++o) {
        float a = 0.f;
#pragma unroll
        for (int j = 0; j < 4; ++j) a += hv[j] * W2[o * 256 + j * 64 + l];
        t[o] = a;
    }
#pragma unroll
    for (int m = 32; m > 0; m >>= 1) {
#pragma unroll
        for (int o = 0; o < 10; ++o) t[o] += __shfl_xor(t[o], m);
    }
    if (l == 0) {
        float as = 0.f, ad = 0.f;
#pragma unroll
        for (int o = 0; o < 10; ++o) {
            h2lin[(size_t)wid * 10 + o] = t[o];
            as += t[o] * as2v[o];
            ad += t[o] * ad2v[o];
        }
        alpha_s2[wid] = as;
        alpha_d2[wid] = ad;
    }
}

// ---------------- gather layer 2 + softmax + bias + fused mean-pool -------
__global__ void k_g2pool(const int* __restrict__ indptr, const int* __restrict__ srcs,
                         const float* __restrict__ als2, const float* __restrict__ ald2,
                         const float* __restrict__ h2lin, const float* __restrict__ b2,
                         const int* __restrict__ batch, float* __restrict__ pooled) {
    int t = blockIdx.x * 256 + threadIdx.x;
    bool valid = t < NN;
    float acc[10] = {};
    int g = -1;
    if (valid) {
        int p0 = indptr[t], p1 = indptr[t + 1];
        float adt = ald2[t];
        float dsum = 0.f;
        for (int p = p0; p < p1; ++p) {
            int s = srcs[p];
            float v = als2[s] + adt;
            v = v > 0.f ? v : 0.2f * v;
            float w = __expf(v);
            dsum += w;
            const float* hr = &h2lin[(size_t)s * 10];
#pragma unroll
            for (int c = 0; c < 10; ++c) acc[c] += w * hr[c];
        }
        float inv = 1.0f / dsum;
#pragma unroll
        for (int c = 0; c < 10; ++c) acc[c] = acc[c] * inv + b2[c];
        g = batch[t];
    }
    int g0 = __shfl(g, 0);
    bool uni = __all((!valid) || (g == g0));
    if (uni) {
        if (g0 >= 0) {
#pragma unroll
            for (int m = 32; m > 0; m >>= 1) {
#pragma unroll
                for (int c = 0; c < 10; ++c) acc[c] += __shfl_xor(acc[c], m);
            }
            if ((threadIdx.x & 63) == 0) {
#pragma unroll
                for (int c = 0; c < 10; ++c) atomicAdd(pooled + g0 * 10 + c, acc[c]);
            }
        }
    } else if (valid) {
#pragma unroll
        for (int c = 0; c < 10; ++c) atomicAdd(pooled + g * 10 + c, acc[c]);
    }
}

// ---------------- mean + log_softmax --------------------------------------
__global__ void k_final(const float* __restrict__ pooled, const int* __restrict__ gcount,
                        float* __restrict__ out) {
    int g = threadIdx.x;
    if (g >= NG) return;
    float c = fmaxf((float)gcount[g], 1.0f);
    float m[10];
    float mx = -1e30f;
#pragma unroll
    for (int i = 0; i < 10; ++i) {
        m[i] = pooled[g * 10 + i] / c;
        mx = fmaxf(mx, m[i]);
    }
    float s = 0.f;
#pragma unroll
    for (int i = 0; i < 10; ++i) s += expf(m[i] - mx);
    float lse = mx + logf(s);
#pragma unroll
    for (int i = 0; i < 10; ++i) out[g * 10 + i] = m[i] - lse;
}

extern "C" void kernel_launch(void* const* d_in, const int* in_sizes, int n_in,
                              void* d_out, int out_size, void* d_ws, size_t ws_size,
                              hipStream_t stream) {
    const float* x   = (const float*)d_in[0];
    const int*   ei  = (const int*)d_in[1];
    const int*   bat = (const int*)d_in[3];
    const float* W1  = (const float*)d_in[4];
    const float* as1 = (const float*)d_in[5];
    const float* ad1 = (const float*)d_in[6];
    const float* b1  = (const float*)d_in[7];
    const float* W2  = (const float*)d_in[8];
    const float* as2 = (const float*)d_in[9];
    const float* ad2 = (const float*)d_in[10];
    const float* b2  = (const float*)d_in[11];
    float* out = (float*)d_out;

    char* ws = (char*)d_ws;
    size_t off = 0;
    auto alloc = [&](size_t bytes) -> size_t {
        size_t o = off;
        off = (off + bytes + 255) & ~(size_t)255;
        return o;
    };
    // zero-initialized region (contiguous, one memset)
    size_t o_counts = alloc((size_t)NN * 4);
    size_t o_pooled = alloc((size_t)NG * 10 * 4);
    size_t o_gcount = alloc((size_t)NG * 4);
    size_t zero_bytes = off;
    // rest (written fully each call by kernels)
    size_t o_cursor = alloc((size_t)NN * 4);
    size_t o_indptr = alloc((size_t)(NN + 1) * 4);
    size_t o_srcs   = alloc((size_t)ETOT * 4);
    size_t o_h1lin  = alloc((size_t)NN * 256 * 4);
    size_t o_h1     = alloc((size_t)NN * 256 * 4);
    size_t o_als1   = alloc((size_t)NN * 4 * 4);
    size_t o_ald1   = alloc((size_t)NN * 4 * 4);
    size_t o_h2lin  = alloc((size_t)NN * 10 * 4);
    size_t o_als2   = alloc((size_t)NN * 4);
    size_t o_ald2   = alloc((size_t)NN * 4);
    (void)ws_size;

    int*   counts = (int*)(ws + o_counts);
    float* pooled = (float*)(ws + o_pooled);
    int*   gcount = (int*)(ws + o_gcount);
    int*   cursor = (int*)(ws + o_cursor);
    int*   indptr = (int*)(ws + o_indptr);
    int*   srcs   = (int*)(ws + o_srcs);
    float* h1lin  = (float*)(ws + o_h1lin);
    float* h1     = (float*)(ws + o_h1);
    float* als1   = (float*)(ws + o_als1);
    float* ald1   = (float*)(ws + o_ald1);
    float* h2lin  = (float*)(ws + o_h2lin);
    float* als2   = (float*)(ws + o_als2);
    float* ald2   = (float*)(ws + o_ald2);

    hipMemsetAsync(ws, 0, zero_bytes, stream);

    int gE = (ETOT + 255) / 256;        // edge-parallel grids
    int gW = (NN + 3) / 4;              // wave-per-node grids (4 waves/block)
    int gN = (NN + 255) / 256;          // thread-per-node grids

    k_hist<<<gE, 256, 0, stream>>>(ei, bat, counts, gcount);
    k_scan<<<1, 1024, 0, stream>>>(counts, indptr, cursor);
    k_gemm1<<<(NN + 31) / 32, 256, 0, stream>>>(x, W1, h1lin);
    k_alpha1<<<gW, 256, 0, stream>>>(h1lin, as1, ad1, als1, ald1);
    k_fill<<<gE, 256, 0, stream>>>(ei, cursor, srcs);
    k_gather1<<<gW, 256, 0, stream>>>(indptr, srcs, als1, ald1, h1lin, b1, h1);
    k_gemm2a<<<gW, 256, 0, stream>>>(h1, W2, as2, ad2, h2lin, als2, ald2);
    k_g2pool<<<gN, 256, 0, stream>>>(indptr, srcs, als2, ald2, h2lin, b2, bat, pooled);
    k_final<<<1, 64, 0, stream>>>(pooled, gcount, out);
    (void)n_in; (void)in_sizes; (void)out_size;
}

// Round 3
// 443.338 us; speedup vs baseline: 2.0674x; 1.1850x over previous
//
#include <hip/hip_runtime.h>
#include <math.h>

#define NN 50000
#define EE 500000
#define ETOT (EE + NN)
#define NG 64

// ---------------- histogram of dst + per-graph node counts ----------------
__global__ void k_hist(const int* __restrict__ ei, const int* __restrict__ batch,
                       int* __restrict__ counts, int* __restrict__ gcount) {
    int t = blockIdx.x * 256 + threadIdx.x;
    if (t < ETOT) {
        int dst = (t < EE) ? ei[EE + t] : (t - EE);
        atomicAdd(counts + dst, 1);
    }
    if (t < NN) {
        int g = batch[t];
        // batch is sorted -> waves are (nearly) uniform. Aggregate per wave.
        int g0 = __shfl(g, 0);
        bool same = (g == g0);
        unsigned long long m = __ballot(same);
        if (same) {
            if ((threadIdx.x & 63) == (__ffsll((long long)m) - 1))
                atomicAdd(gcount + g0, (int)__popcll(m));
        } else {
            atomicAdd(gcount + g, 1);
        }
    }
}

// ---------------- exclusive scan counts -> indptr (+ seed cursor) ---------
__global__ void k_scan(const int* __restrict__ counts, int* __restrict__ indptr,
                       int* __restrict__ cursor) {
    __shared__ int wsum[16];
    __shared__ int carry_s;
    int tid = threadIdx.x;
    int lane = tid & 63;
    int w = tid >> 6;
    if (tid == 0) carry_s = 0;
    __syncthreads();
    for (int base = 0; base < NN; base += 1024) {
        int i = base + tid;
        int v = (i < NN) ? counts[i] : 0;
        int s = v;
#pragma unroll
        for (int off = 1; off < 64; off <<= 1) {
            int u = __shfl_up(s, off);
            if (lane >= off) s += u;
        }
        if (lane == 63) wsum[w] = s;
        __syncthreads();
        if (w == 0) {
            int t2 = (lane < 16) ? wsum[lane] : 0;
#pragma unroll
            for (int off = 1; off < 16; off <<= 1) {
                int u = __shfl_up(t2, off);
                if (lane >= off) t2 += u;
            }
            if (lane < 16) wsum[lane] = t2;
        }
        __syncthreads();
        int wpre = (w == 0) ? 0 : wsum[w - 1];
        int incl = s + wpre;
        int carry = carry_s;
        if (i < NN) {
            int excl = carry + incl - v;
            indptr[i] = excl;
            cursor[i] = excl;
        }
        __syncthreads();
        if (tid == 1023) carry_s = carry + incl;
        __syncthreads();
    }
    if (tid == 0) indptr[NN] = carry_s;
}

// ---------------- GEMM1: h1lin[N,256] = x[N,128] @ W1[256,128]^T ----------
// LDS-tiled: BM=128 rows, BN=128 cols (2 col-blocks), BK=32.
// 256 threads, 8x8 microtile, interleaved mapping row=tr+16i, col=tc+16j
// so ds_read_b128 is <=2-way bank conflicted (free). Row pad +4 (stride 36).
__global__ __launch_bounds__(256) void k_gemm1(const float* __restrict__ x,
                                               const float* __restrict__ W1,
                                               float* __restrict__ h1lin) {
    __shared__ float As[128][36];
    __shared__ float Bs[128][36];
    int tid = threadIdx.x;
    int nb = blockIdx.x >> 1;          // row block (0..390)
    int cb = blockIdx.x & 1;           // col block (0..1)
    int bm0 = nb * 128;
    int bn0 = cb * 128;
    int tr = tid >> 4;                 // 0..15
    int tc = tid & 15;                 // 0..15
    float acc[8][8] = {};
    for (int k0 = 0; k0 < 128; k0 += 32) {
        // stage A: 128 rows x 32 k (4 float4 per thread)
#pragma unroll
        for (int it = 0; it < 4; ++it) {
            int lin = (it * 256 + tid) * 4;
            int r = lin >> 5, c = lin & 31;
            int gr = bm0 + r;
            float4 v = make_float4(0.f, 0.f, 0.f, 0.f);
            if (gr < NN) v = *(const float4*)&x[(size_t)gr * 128 + k0 + c];
            *(float4*)&As[r][c] = v;
        }
        // stage B: W1 rows bn0..bn0+127 (output cols), 32 k
#pragma unroll
        for (int it = 0; it < 4; ++it) {
            int lin = (it * 256 + tid) * 4;
            int r = lin >> 5, c = lin & 31;
            *(float4*)&Bs[r][c] = *(const float4*)&W1[(size_t)(bn0 + r) * 128 + k0 + c];
        }
        __syncthreads();
#pragma unroll
        for (int kk = 0; kk < 32; kk += 4) {
            float4 av[8], bv[8];
#pragma unroll
            for (int i = 0; i < 8; ++i) av[i] = *(const float4*)&As[tr + 16 * i][kk];
#pragma unroll
            for (int j = 0; j < 8; ++j) bv[j] = *(const float4*)&Bs[tc + 16 * j][kk];
#pragma unroll
            for (int i = 0; i < 8; ++i)
#pragma unroll
                for (int j = 0; j < 8; ++j)
                    acc[i][j] += av[i].x * bv[j].x + av[i].y * bv[j].y +
                                 av[i].z * bv[j].z + av[i].w * bv[j].w;
        }
        __syncthreads();
    }
#pragma unroll
    for (int i = 0; i < 8; ++i) {
        int gr = bm0 + tr + 16 * i;
        if (gr < NN) {
#pragma unroll
            for (int j = 0; j < 8; ++j)
                h1lin[(size_t)gr * 256 + bn0 + tc + 16 * j] = acc[i][j];
        }
    }
}

// ---------------- per-node attention logits layer 1 -----------------------
__global__ void k_alpha1(const float* __restrict__ h1lin, const float* __restrict__ att_s,
                         const float* __restrict__ att_d, float* __restrict__ alpha_s,
                         float* __restrict__ alpha_d) {
    int wid = (blockIdx.x * 256 + threadIdx.x) >> 6;
    int l = threadIdx.x & 63;
    if (wid >= NN) return;
    float s[4], d[4];
#pragma unroll
    for (int j = 0; j < 4; ++j) {
        float h = h1lin[(size_t)wid * 256 + j * 64 + l];
        s[j] = h * att_s[j * 64 + l];
        d[j] = h * att_d[j * 64 + l];
    }
#pragma unroll
    for (int m = 32; m > 0; m >>= 1) {
#pragma unroll
        for (int j = 0; j < 4; ++j) {
            s[j] += __shfl_xor(s[j], m);
            d[j] += __shfl_xor(d[j], m);
        }
    }
    if (l == 0) {
#pragma unroll
        for (int j = 0; j < 4; ++j) {
            alpha_s[wid * 4 + j] = s[j];
            alpha_d[wid * 4 + j] = d[j];
        }
    }
}

// ---------------- bucket fill (CSR column indices) ------------------------
__global__ void k_fill(const int* __restrict__ ei, int* __restrict__ cursor,
                       int* __restrict__ srcs) {
    int t = blockIdx.x * 256 + threadIdx.x;
    if (t >= ETOT) return;
    int src = (t < EE) ? ei[t] : (t - EE);
    int dst = (t < EE) ? ei[EE + t] : (t - EE);
    int p = atomicAdd(cursor + dst, 1);
    srcs[p] = src;
}

// ---------------- gather-aggregate layer 1 + softmax + bias + ELU ---------
__global__ void k_gather1(const int* __restrict__ indptr, const int* __restrict__ srcs,
                          const float* __restrict__ alpha_s, const float* __restrict__ alpha_d,
                          const float* __restrict__ h1lin, const float* __restrict__ b1,
                          float* __restrict__ h1) {
    int wid = (blockIdx.x * 256 + threadIdx.x) >> 6;
    int l = threadIdx.x & 63;
    if (wid >= NN) return;
    int p0 = indptr[wid], p1 = indptr[wid + 1];
    float4 ad = *(const float4*)&alpha_d[wid * 4];
    float acc[4] = {0.f, 0.f, 0.f, 0.f};
    float dsum[4] = {0.f, 0.f, 0.f, 0.f};
    for (int p = p0; p < p1; ++p) {
        int s = srcs[p];
        float4 as = *(const float4*)&alpha_s[s * 4];
        float e[4];
        e[0] = as.x + ad.x; e[1] = as.y + ad.y; e[2] = as.z + ad.z; e[3] = as.w + ad.w;
        const float* hs = &h1lin[(size_t)s * 256 + l];
#pragma unroll
        for (int j = 0; j < 4; ++j) {
            float v = e[j] > 0.f ? e[j] : 0.2f * e[j];
            float w = __expf(v);
            dsum[j] += w;
            acc[j] += w * hs[j * 64];
        }
    }
#pragma unroll
    for (int j = 0; j < 4; ++j) {
        float v = acc[j] / dsum[j] + b1[j * 64 + l];
        v = v > 0.f ? v : expm1f(v);
        h1[(size_t)wid * 256 + j * 64 + l] = v;
    }
}

// ---------------- GEMM2 (wave/node) + attention logits layer 2 ------------
__global__ void k_gemm2a(const float* __restrict__ h1, const float* __restrict__ W2,
                         const float* __restrict__ as2v, const float* __restrict__ ad2v,
                         float* __restrict__ h2lin, float* __restrict__ alpha_s2,
                         float* __restrict__ alpha_d2) {
    int wid = (blockIdx.x * 256 + threadIdx.x) >> 6;
    int l = threadIdx.x & 63;
    if (wid >= NN) return;
    float hv[4];
#pragma unroll
    for (int j = 0; j < 4; ++j) hv[j] = h1[(size_t)wid * 256 + j * 64 + l];
    float t[10];
#pragma unroll
    for (int o = 0; o < 10; ++o) {
        float a = 0.f;
#pragma unroll
        for (int j = 0; j < 4; ++j) a += hv[j] * W2[o * 256 + j * 64 + l];
        t[o] = a;
    }
#pragma unroll
    for (int m = 32; m > 0; m >>= 1) {
#pragma unroll
        for (int o = 0; o < 10; ++o) t[o] += __shfl_xor(t[o], m);
    }
    if (l == 0) {
        float as = 0.f, ad = 0.f;
#pragma unroll
        for (int o = 0; o < 10; ++o) {
            h2lin[(size_t)wid * 10 + o] = t[o];
            as += t[o] * as2v[o];
            ad += t[o] * ad2v[o];
        }
        alpha_s2[wid] = as;
        alpha_d2[wid] = ad;
    }
}

// ---------------- gather layer 2 + softmax + bias + fused mean-pool -------
__global__ void k_g2pool(const int* __restrict__ indptr, const int* __restrict__ srcs,
                         const float* __restrict__ als2, const float* __restrict__ ald2,
                         const float* __restrict__ h2lin, const float* __restrict__ b2,
                         const int* __restrict__ batch, float* __restrict__ pooled) {
    int t = blockIdx.x * 256 + threadIdx.x;
    bool valid = t < NN;
    float acc[10] = {};
    int g = -1;
    if (valid) {
        int p0 = indptr[t], p1 = indptr[t + 1];
        float adt = ald2[t];
        float dsum = 0.f;
        for (int p = p0; p < p1; ++p) {
            int s = srcs[p];
            float v = als2[s] + adt;
            v = v > 0.f ? v : 0.2f * v;
            float w = __expf(v);
            dsum += w;
            const float* hr = &h2lin[(size_t)s * 10];
#pragma unroll
            for (int c = 0; c < 10; ++c) acc[c] += w * hr[c];
        }
        float inv = 1.0f / dsum;
#pragma unroll
        for (int c = 0; c < 10; ++c) acc[c] = acc[c] * inv + b2[c];
        g = batch[t];
    }
    int g0 = __shfl(g, 0);
    bool uni = __all((!valid) || (g == g0));
    if (uni) {
        if (g0 >= 0) {
#pragma unroll
            for (int m = 32; m > 0; m >>= 1) {
#pragma unroll
                for (int c = 0; c < 10; ++c) acc[c] += __shfl_xor(acc[c], m);
            }
            if ((threadIdx.x & 63) == 0) {
#pragma unroll
                for (int c = 0; c < 10; ++c) atomicAdd(pooled + g0 * 10 + c, acc[c]);
            }
        }
    } else if (valid) {
#pragma unroll
        for (int c = 0; c < 10; ++c) atomicAdd(pooled + g * 10 + c, acc[c]);
    }
}

// ---------------- mean + log_softmax --------------------------------------
__global__ void k_final(const float* __restrict__ pooled, const int* __restrict__ gcount,
                        float* __restrict__ out) {
    int g = threadIdx.x;
    if (g >= NG) return;
    float c = fmaxf((float)gcount[g], 1.0f);
    float m[10];
    float mx = -1e30f;
#pragma unroll
    for (int i = 0; i < 10; ++i) {
        m[i] = pooled[g * 10 + i] / c;
        mx = fmaxf(mx, m[i]);
    }
    float s = 0.f;
#pragma unroll
    for (int i = 0; i < 10; ++i) s += expf(m[i] - mx);
    float lse = mx + logf(s);
#pragma unroll
    for (int i = 0; i < 10; ++i) out[g * 10 + i] = m[i] - lse;
}

extern "C" void kernel_launch(void* const* d_in, const int* in_sizes, int n_in,
                              void* d_out, int out_size, void* d_ws, size_t ws_size,
                              hipStream_t stream) {
    const float* x   = (const float*)d_in[0];
    const int*   ei  = (const int*)d_in[1];
    const int*   bat = (const int*)d_in[3];
    const float* W1  = (const float*)d_in[4];
    const float* as1 = (const float*)d_in[5];
    const float* ad1 = (const float*)d_in[6];
    const float* b1  = (const float*)d_in[7];
    const float* W2  = (const float*)d_in[8];
    const float* as2 = (const float*)d_in[9];
    const float* ad2 = (const float*)d_in[10];
    const float* b2  = (const float*)d_in[11];
    float* out = (float*)d_out;

    char* ws = (char*)d_ws;
    size_t off = 0;
    auto alloc = [&](size_t bytes) -> size_t {
        size_t o = off;
        off = (off + bytes + 255) & ~(size_t)255;
        return o;
    };
    // zero-initialized region (contiguous, one memset)
    size_t o_counts = alloc((size_t)NN * 4);
    size_t o_pooled = alloc((size_t)NG * 10 * 4);
    size_t o_gcount = alloc((size_t)NG * 4);
    size_t zero_bytes = off;
    // rest (written fully each call by kernels)
    size_t o_cursor = alloc((size_t)NN * 4);
    size_t o_indptr = alloc((size_t)(NN + 1) * 4);
    size_t o_srcs   = alloc((size_t)ETOT * 4);
    size_t o_h1lin  = alloc((size_t)NN * 256 * 4);
    size_t o_h1     = alloc((size_t)NN * 256 * 4);
    size_t o_als1   = alloc((size_t)NN * 4 * 4);
    size_t o_ald1   = alloc((size_t)NN * 4 * 4);
    size_t o_h2lin  = alloc((size_t)NN * 10 * 4);
    size_t o_als2   = alloc((size_t)NN * 4);
    size_t o_ald2   = alloc((size_t)NN * 4);
    (void)ws_size;

    int*   counts = (int*)(ws + o_counts);
    float* pooled = (float*)(ws + o_pooled);
    int*   gcount = (int*)(ws + o_gcount);
    int*   cursor = (int*)(ws + o_cursor);
    int*   indptr = (int*)(ws + o_indptr);
    int*   srcs   = (int*)(ws + o_srcs);
    float* h1lin  = (float*)(ws + o_h1lin);
    float* h1     = (float*)(ws + o_h1);
    float* als1   = (float*)(ws + o_als1);
    float* ald1   = (float*)(ws + o_ald1);
    float* h2lin  = (float*)(ws + o_h2lin);
    float* als2   = (float*)(ws + o_als2);
    float* ald2   = (float*)(ws + o_ald2);

    hipMemsetAsync(ws, 0, zero_bytes, stream);

    int gE = (ETOT + 255) / 256;        // edge-parallel grids
    int gW = (NN + 3) / 4;              // wave-per-node grids (4 waves/block)
    int gN = (NN + 255) / 256;          // thread-per-node grids

    k_hist<<<gE, 256, 0, stream>>>(ei, bat, counts, gcount);
    k_scan<<<1, 1024, 0, stream>>>(counts, indptr, cursor);
    k_gemm1<<<391 * 2, 256, 0, stream>>>(x, W1, h1lin);
    k_alpha1<<<gW, 256, 0, stream>>>(h1lin, as1, ad1, als1, ald1);
    k_fill<<<gE, 256, 0, stream>>>(ei, cursor, srcs);
    k_gather1<<<gW, 256, 0, stream>>>(indptr, srcs, als1, ald1, h1lin, b1, h1);
    k_gemm2a<<<gW, 256, 0, stream>>>(h1, W2, as2, ad2, h2lin, als2, ald2);
    k_g2pool<<<gN, 256, 0, stream>>>(indptr, srcs, als2, ald2, h2lin, b2, bat, pooled);
    k_final<<<1, 64, 0, stream>>>(pooled, gcount, out);
    (void)n_in; (void)in_sizes; (void)out_size;
}